// Round 12
// baseline (982.586 us; speedup 1.0000x reference)
//
#include <hip/hip_runtime.h>
#include <hip/hip_bf16.h>

#define NN      2048
#define NSTEPS  2047
#define MROWS   8192
#define PADK    8

typedef __attribute__((ext_vector_type(8))) __bf16 bf16x8;
typedef __attribute__((ext_vector_type(4))) float  f32x4;
typedef __attribute__((ext_vector_type(2))) float  f32x2;

__device__ __forceinline__ unsigned short f2bf(float f) {
  unsigned int u = __float_as_uint(f);
  u += 0x7fffu + ((u >> 16) & 1u);   // RNE
  return (unsigned short)(u >> 16);
}

__device__ __forceinline__ void gload_lds16(const void* g, void* l) {
  __builtin_amdgcn_global_load_lds((const __attribute__((address_space(1))) void*)g,
                                   (__attribute__((address_space(3))) void*)l, 16, 0, 0);
}

// DPP wave-wide lane shifts (VALU pipe). Verified rounds 6-11.
template<int CTRL>
__device__ __forceinline__ float dppf(float v) {
  return __int_as_float(__builtin_amdgcn_update_dpp(
      __float_as_int(v), __float_as_int(v), CTRL, 0xf, 0xf, false));
}
#define DPP_UP 0x138
#define DPP_DN 0x130

// Packed fp32 rotation math. Verified rounds 7-11.
__device__ __forceinline__ f32x2 pk_smul(f32x2 cs, f32x2 v) {
  f32x2 d;
  asm("v_pk_mul_f32 %0, %1, %2 op_sel:[1,0] op_sel_hi:[1,1]"
      : "=v"(d) : "v"(cs), "v"(v));
  return d;
}
__device__ __forceinline__ f32x2 pk_cfma(f32x2 cs, f32x2 v, f32x2 a) {
  f32x2 d;
  asm("v_pk_fma_f32 %0, %1, %2, %3 op_sel:[0,0,0] op_sel_hi:[0,1,1]"
      : "=v"(d) : "v"(cs), "v"(v), "v"(a));
  return d;
}
__device__ __forceinline__ f32x2 pk_cfma_neg(f32x2 cs, f32x2 v, f32x2 a) {
  f32x2 d;
  asm("v_pk_fma_f32 %0, %1, %2, %3 op_sel:[0,0,0] op_sel_hi:[0,1,1] neg_lo:[0,0,1] neg_hi:[0,0,1]"
      : "=v"(d) : "v"(cs), "v"(v), "v"(a));
  return d;
}

// ---- angles -> (cos,sin), layout cs[step][pair] (8 KB/slice)
__global__ __launch_bounds__(256) void prep_kernel(
    const float* __restrict__ angles, float2* __restrict__ cs) {
  int idx = blockIdx.x * 256 + threadIdx.x;
  if (idx >= NSTEPS * 1024) return;
  float s, c;
  sincosf(angles[idx], &s, &c);
  cs[idx] = make_float2(c, s);
}

// ---- x fp32 -> bf16
__global__ __launch_bounds__(256) void cvt_kernel(
    const float4* __restrict__ x, ushort4* __restrict__ xb, int n4) {
  int idx = blockIdx.x * 256 + threadIdx.x;
  if (idx >= n4) return;
  float4 v = x[idx];
  ushort4 o;
  o.x = f2bf(v.x); o.y = f2bf(v.y); o.z = f2bf(v.z); o.w = f2bf(v.w);
  xb[idx] = o;
}

// ---- zero scratch region
__global__ __launch_bounds__(256) void zero_kernel(uint4* __restrict__ p, int n) {
  int idx = blockIdx.x * 256 + threadIdx.x;
  const int stride = gridDim.x * 256;
  const uint4 z = make_uint4(0, 0, 0, 0);
  for (; idx < n; idx += stride) p[idx] = z;
}

// ---- leaf: build chunk matrix B_c = M_{t0}...M_{t0+LC-1} rows by windowed conveyor.
// Window = 512 pairs (8/lane, mod-8 reg phases = round-10 verified machinery), but
// wave-autonomous: no barriers, no exchange. Window edges inject 0 (support can't
// escape); pair-0/1023 reflections reuse the verified q0/q3 specials (KB0/KBT).
// Wave owns 2 POSITION-adjacent rows (positions 2v, 2v+1 at t0) as f32x2.
template<int LC>
__global__ __launch_bounds__(256) void leaf_kernel(
    const char* __restrict__ csb, unsigned short* __restrict__ o0,
    unsigned short* __restrict__ o1, unsigned short* __restrict__ o2,
    int c_base, int first_rm) {
  const int tid  = threadIdx.x;
  const int lane = tid & 63;
  const int cl   = blockIdx.x >> 8;                      // chunk-local 0..2
  const int v    = ((blockIdx.x & 255) << 2) + (tid >> 6);
  const int c    = c_base + cl;
  const int t0   = 254 * c;
  unsigned short* out = (cl == 0) ? o0 : ((cl == 1) ? o1 : o2);
  const bool rm = (first_rm != 0) && (cl == 0);

  const int pA = 2 * v, pB = 2 * v + 1;
  const int kA = (pA <= 1023) ? pA : 2047 - pA;
  const int kBp = (pB <= 1023) ? pB : 2047 - pB;
  const int kmin = min(kA, kBp);
  int kb = (kmin - 254) & ~1;
  kb = min(max(kb, 0), 512);
  const bool l0 = (lane == 0), l63 = (lane == 63);
  const bool c0l0  = (kb == 0)   && l0;
  const bool cTl63 = (kb == 512) && l63;

  // state: elem e <-> pair k = kb + 8*lane + e; F slot = pos k, S slot = pos 2047-k
  f32x2 FF[8], SS[8];
#pragma unroll
  for (int e = 0; e < 8; ++e) {
    const int k = kb + 8 * lane + e, m = 2047 - k;
    FF[e] = (f32x2){(k == pA) ? 1.f : 0.f, (k == pB) ? 1.f : 0.f};
    SS[e] = (f32x2){(m == pA) ? 1.f : 0.f, (m == pB) ? 1.f : 0.f};
  }

  // cs: lane's 8 pairs = 64B at slice + kb*8 + 64*lane (kb even -> 16B aligned)
  const char* gpE = csb + (size_t)t0 * 8192 + kb * 8 + 64 * lane;
  const char* gpO = gpE + 8192;
  float4 cE0 = ((const float4*)gpE)[0], cE1 = ((const float4*)gpE)[1];
  float4 cE2 = ((const float4*)gpE)[2], cE3 = ((const float4*)gpE)[3];
  float4 cO0 = ((const float4*)gpO)[0], cO1 = ((const float4*)gpO)[1];
  float4 cO2 = ((const float4*)gpO)[2], cO3 = ((const float4*)gpO)[3];
  gpE += 16384; gpO += 16384;

#define CP(CV, K) (((const f32x2*)&(CV))[(K)])

#define ROTE(E, CPp) { \
    const int rF = ((E) - PHI) & 7, rS = ((E) + PHI) & 7; \
    const f32x2 cp_ = (CPp); \
    const f32x2 t_ = pk_smul(cp_, SS[rS]); \
    const f32x2 u_ = pk_smul(cp_, FF[rF]); \
    FF[rF] = pk_cfma(cp_, FF[rF], t_); \
    SS[rS] = pk_cfma_neg(cp_, SS[rS], u_); }

#define LSTEP(PHI_, C0, C1, C2, C3, GP) { \
    const int PHI = (PHI_); \
    const int pF = (7 - PHI) & 7, pT = (8 - PHI) & 7; \
    ROTE(0, CP(C0, 0)) ROTE(1, CP(C0, 1)) \
    ROTE(2, CP(C1, 0)) ROTE(3, CP(C1, 1)) \
    ROTE(4, CP(C2, 0)) ROTE(5, CP(C2, 1)) \
    ROTE(6, CP(C3, 0)) ROTE(7, CP(C3, 1)) \
    const f32x2 Fo = FF[pF], So = SS[PHI], St = FF[pT]; \
    f32x2 fi, sd; \
    fi.x = dppf<DPP_UP>(Fo.x); fi.y = dppf<DPP_UP>(Fo.y); \
    sd.x = dppf<DPP_DN>(So.x); sd.y = dppf<DPP_DN>(So.y); \
    C0 = ((const float4*)GP)[0]; C1 = ((const float4*)GP)[1]; \
    C2 = ((const float4*)GP)[2]; C3 = ((const float4*)GP)[3]; \
    GP += 16384; \
    const f32x2 z2 = {0.f, 0.f}; \
    const f32x2 xF = c0l0 ? St : z2; \
    const f32x2 xS = cTl63 ? Fo : z2; \
    FF[pF]  = l0  ? xF : fi; \
    SS[PHI] = l63 ? xS : sd; \
    FF[pT]  = c0l0 ? So : FF[pT]; \
  }

  constexpr int ITERS = LC / 8;
  constexpr int TAIL  = LC & 7;
#pragma unroll 1
  for (int it = 0; it < ITERS; ++it) {
    LSTEP(0, cE0, cE1, cE2, cE3, gpE)
    LSTEP(1, cO0, cO1, cO2, cO3, gpO)
    LSTEP(2, cE0, cE1, cE2, cE3, gpE)
    LSTEP(3, cO0, cO1, cO2, cO3, gpO)
    LSTEP(4, cE0, cE1, cE2, cE3, gpE)
    LSTEP(5, cO0, cO1, cO2, cO3, gpO)
    LSTEP(6, cE0, cE1, cE2, cE3, gpE)
    LSTEP(7, cO0, cO1, cO2, cO3, gpO)
  }
  if constexpr (TAIL >= 1) LSTEP(0, cE0, cE1, cE2, cE3, gpE)
  if constexpr (TAIL >= 2) LSTEP(1, cO0, cO1, cO2, cO3, gpO)
  if constexpr (TAIL >= 3) LSTEP(2, cE0, cE1, cE2, cE3, gpE)
  if constexpr (TAIL >= 4) LSTEP(3, cO0, cO1, cO2, cO3, gpO)
  if constexpr (TAIL >= 5) LSTEP(4, cE0, cE1, cE2, cE3, gpE)
  if constexpr (TAIL >= 6) LSTEP(5, cO0, cO1, cO2, cO3, gpO)
  if constexpr (TAIL >= 7) LSTEP(6, cE0, cE1, cE2, cE3, gpE)

  // readout at T=LC: F elem e in FF[(e-LC)&7]; S elem e in SS[(e+LC)&7].
  // row labels: r = label(p, t0); col labels: l = label(pos, t0+LC).
  constexpr int RPH = LC & 7;
  const int tend = t0 + LC;
  const int rA = (pA == 0) ? 0 : ((pA - 1 - t0 + 4094) % 2047) + 1;
  const int rB = ((pB - 1 - t0 + 4094) % 2047) + 1;
#pragma unroll
  for (int e = 0; e < 8; ++e) {
    const int k = kb + 8 * lane + e;
    const int lF = (k == 0) ? 0 : ((k - 1 - tend + 4094) % 2047) + 1;
    const int lS = ((2046 - k - tend + 4094) % 2047) + 1;
    const f32x2 fv = FF[(e - RPH) & 7];
    const f32x2 sv = SS[(e + RPH) & 7];
    if (rm) {
      out[(size_t)rA * NN + lF] = f2bf(fv.x);
      out[(size_t)rB * NN + lF] = f2bf(fv.y);
      out[(size_t)rA * NN + lS] = f2bf(sv.x);
      out[(size_t)rB * NN + lS] = f2bf(sv.y);
    } else {
      out[(size_t)lF * NN + rA] = f2bf(fv.x);
      out[(size_t)lF * NN + rB] = f2bf(fv.y);
      out[(size_t)lS * NN + rA] = f2bf(sv.x);
      out[(size_t)lS * NN + rB] = f2bf(sv.y);
    }
  }
}

// κ-range of a cyclic position arc [a, a+len-1] in [1..2047], κ(p)=min(p,2047-p)
__device__ __forceinline__ void arc_kr(int a, int len, int& lo, int& hi) {
  int last = a + len - 1; if (last > 2047) last -= 2047;
  const int k1 = min(a, 2047 - a), k2 = min(last, 2047 - last);
  lo = min(k1, k2); hi = max(k1, k2);
  int d;
  d = 1023 - a; if (d < 0) d += 2047; if (d < len) hi = 1023;
  d = 1024 - a; if (d < 0) d += 2047; if (d < len) hi = 1023;
  d = 2047 - a; if (d < 0) d += 2047; if (d < len) lo = 0;
  d = 1    - a; if (d < 0) d += 2047; if (d < len) lo = min(lo, 1);
}

#define BM 128
#define BN 128
#define BK 32

// ---- comp: C = A * Bt^T (2048^3), bf16 out, K-tiles band-skipped by cone test.
// Bt = B_c^T (chunk matrix, time range [ta,tb)): B_c[k,n] != 0 only if
// kappa(pos_ta(k)) within (tb-ta) of kappa(pos_tb(n)). Block-uniform skip -> barrier-safe.
__global__ __launch_bounds__(256) void comp_kernel(
    const unsigned short* __restrict__ A, const unsigned short* __restrict__ B,
    unsigned short* __restrict__ C, int ta, int tb) {
  __shared__ unsigned short As[BM * BK];
  __shared__ unsigned short Bs[BN * BK];
  const int tid  = threadIdx.x;
  const int lane = tid & 63;
  const int wave = tid >> 6;
  const int bm = blockIdx.x, bn = blockIdx.y;
  const int wm = wave & 1, wn = wave >> 1;

  // band cone for this n-tile
  const int n0 = bn * BN;
  int qlo, qhi;
  {
    const int nfirst = (n0 == 0) ? 1 : n0;
    const int a = ((nfirst - 1 + tb) % 2047) + 1;
    const int len = (n0 == 0) ? (BN - 1) : BN;
    arc_kr(a, len, qlo, qhi);
    if (n0 == 0) qlo = 0;
  }
  const int L = tb - ta;
  const int KAc = max(qlo - L - PADK, 0);
  const int KBc = min(qhi + L + PADK, 1023);

  const int srow = wave * 16 + (lane >> 2);
  const int scol = (lane & 3) * 8;
  const unsigned short* Ag = A + (size_t)(bm * BM + srow) * NN + scol;
  const unsigned short* Bg = B + (size_t)(bn * BN + srow) * NN + scol;

  const int fm = lane & 15;
  const int kbr = lane >> 4;

  f32x4 acc[4][4];
#pragma unroll
  for (int a_ = 0; a_ < 4; ++a_)
#pragma unroll
    for (int b_ = 0; b_ < 4; ++b_) acc[a_][b_] = (f32x4){0.f, 0.f, 0.f, 0.f};

  for (int kt = 0; kt < NN / BK; ++kt) {
    // k-tile band test (block-uniform)
    const int k0 = kt * BK;
    {
      const int kfirst = (k0 == 0) ? 1 : k0;
      const int a2 = ((kfirst - 1 + ta) % 2047) + 1;
      const int len2 = (k0 == 0) ? (BK - 1) : BK;
      int tlo, thi; arc_kr(a2, len2, tlo, thi);
      if (k0 == 0) tlo = 0;
      if (thi < KAc || tlo > KBc) continue;
    }
#pragma unroll
    for (int it = 0; it < 2; ++it) {
      gload_lds16(Ag + (size_t)(it * 64) * NN + k0, &As[wave * 512 + it * 2048]);
      gload_lds16(Bg + (size_t)(it * 64) * NN + k0, &Bs[wave * 512 + it * 2048]);
    }
    __syncthreads();

    bf16x8 af[4], bfr[4];
#pragma unroll
    for (int a_ = 0; a_ < 4; ++a_)
      af[a_] = *(const bf16x8*)&As[(wm * 64 + a_ * 16 + fm) * BK + kbr * 8];
#pragma unroll
    for (int b_ = 0; b_ < 4; ++b_)
      bfr[b_] = *(const bf16x8*)&Bs[(wn * 64 + b_ * 16 + fm) * BK + kbr * 8];
#pragma unroll
    for (int a_ = 0; a_ < 4; ++a_)
#pragma unroll
      for (int b_ = 0; b_ < 4; ++b_)
        acc[a_][b_] = __builtin_amdgcn_mfma_f32_16x16x32_bf16(af[a_], bfr[b_], acc[a_][b_], 0, 0, 0);
    __syncthreads();
  }

  const int row_in = (lane >> 4) * 4;
#pragma unroll
  for (int a_ = 0; a_ < 4; ++a_) {
#pragma unroll
    for (int b_ = 0; b_ < 4; ++b_) {
      const int gn = bn * BN + wn * 64 + b_ * 16 + fm;
#pragma unroll
      for (int v = 0; v < 4; ++v) {
        const int gm = bm * BM + wm * 64 + a_ * 16 + row_in + v;
        C[(size_t)gm * NN + gn] = f2bf(acc[a_][b_][v]);
      }
    }
  }
}

// ---- final: out = x_bf16 * U^T + bias (fp32 out). Verified rounds 1-11.
__global__ __launch_bounds__(256) void gemm_kernel(
    const unsigned short* __restrict__ A, const unsigned short* __restrict__ B,
    const float* __restrict__ bias, float* __restrict__ C) {
  __shared__ unsigned short As[BM * BK];
  __shared__ unsigned short Bs[BN * BK];
  const int tid  = threadIdx.x;
  const int lane = tid & 63;
  const int wave = tid >> 6;
  const int bm = blockIdx.x, bn = blockIdx.y;
  const int wm = wave & 1, wn = wave >> 1;

  const int srow = wave * 16 + (lane >> 2);
  const int scol = (lane & 3) * 8;
  const unsigned short* Ag = A + (size_t)(bm * BM + srow) * NN + scol;
  const unsigned short* Bg = B + (size_t)(bn * BN + srow) * NN + scol;

  const int fm = lane & 15;
  const int kbr = lane >> 4;

  f32x4 acc[4][4];
#pragma unroll
  for (int a_ = 0; a_ < 4; ++a_)
#pragma unroll
    for (int b_ = 0; b_ < 4; ++b_) acc[a_][b_] = (f32x4){0.f, 0.f, 0.f, 0.f};

  for (int kt = 0; kt < NN / BK; ++kt) {
    const int k0 = kt * BK;
#pragma unroll
    for (int it = 0; it < 2; ++it) {
      gload_lds16(Ag + (size_t)(it * 64) * NN + k0, &As[wave * 512 + it * 2048]);
      gload_lds16(Bg + (size_t)(it * 64) * NN + k0, &Bs[wave * 512 + it * 2048]);
    }
    __syncthreads();

    bf16x8 af[4], bfr[4];
#pragma unroll
    for (int a_ = 0; a_ < 4; ++a_)
      af[a_] = *(const bf16x8*)&As[(wm * 64 + a_ * 16 + fm) * BK + kbr * 8];
#pragma unroll
    for (int b_ = 0; b_ < 4; ++b_)
      bfr[b_] = *(const bf16x8*)&Bs[(wn * 64 + b_ * 16 + fm) * BK + kbr * 8];
#pragma unroll
    for (int a_ = 0; a_ < 4; ++a_)
#pragma unroll
      for (int b_ = 0; b_ < 4; ++b_)
        acc[a_][b_] = __builtin_amdgcn_mfma_f32_16x16x32_bf16(af[a_], bfr[b_], acc[a_][b_], 0, 0, 0);
    __syncthreads();
  }

  const int row_in = (lane >> 4) * 4;
#pragma unroll
  for (int a_ = 0; a_ < 4; ++a_) {
#pragma unroll
    for (int b_ = 0; b_ < 4; ++b_) {
      const int gn = bn * BN + wn * 64 + b_ * 16 + fm;
      const float bv = bias[gn];
#pragma unroll
      for (int v = 0; v < 4; ++v) {
        const int gm = bm * BM + wm * 64 + a_ * 16 + row_in + v;
        C[(size_t)gm * NN + gn] = acc[a_][b_][v] + bv;
      }
    }
  }
}

extern "C" void kernel_launch(void* const* d_in, const int* in_sizes, int n_in,
                              void* d_out, int out_size, void* d_ws, size_t ws_size,
                              hipStream_t stream) {
  const float* x      = (const float*)d_in[0];
  const float* angles = (const float*)d_in[1];
  const float* bias   = (const float*)d_in[2];
  float* out = (float*)d_out;

  char* ws = (char*)d_ws;
  unsigned short* P0  = (unsigned short*)(ws + 0);         //  8,388,608
  unsigned short* P1  = (unsigned short*)(ws + 8388608);   //  8,388,608
  char*           cs  = ws + 16777216;                     // 16,809,984 (2052 slices, >= 2049 needed)
  unsigned short* Bs0 = (unsigned short*)(ws + 33587200);  //  8,388,608
  unsigned short* Bs1 = (unsigned short*)(ws + 41975808);  //  8,388,608
  unsigned short* Bs2 = (unsigned short*)(ws + 50364416);  //  8,388,608 -> end 58,753,024
  unsigned short* xb  = (unsigned short*)(ws + 16777216);  // overlay on cs+B after comps

  prep_kernel<<<dim3(8188), dim3(256), 0, stream>>>(angles, (float2*)cs);
  zero_kernel<<<dim3(2048), dim3(256), 0, stream>>>((uint4*)P0, 8388608 / 16);
  zero_kernel<<<dim3(4096), dim3(256), 0, stream>>>((uint4*)(ws + 33587200), 25165824 / 16);

  // chunks 0,1,2  (chunk 0 -> P0 row-major; 1,2 -> transposed)
  leaf_kernel<254><<<dim3(768), dim3(256), 0, stream>>>(cs, P0, Bs0, Bs1, 0, 1);
  comp_kernel<<<dim3(16, 16), dim3(256), 0, stream>>>(P0, Bs0, P1, 254, 508);
  comp_kernel<<<dim3(16, 16), dim3(256), 0, stream>>>(P1, Bs1, P0, 508, 762);

  zero_kernel<<<dim3(4096), dim3(256), 0, stream>>>((uint4*)(ws + 33587200), 25165824 / 16);
  // chunks 3,4,5
  leaf_kernel<254><<<dim3(768), dim3(256), 0, stream>>>(cs, Bs0, Bs1, Bs2, 3, 0);
  comp_kernel<<<dim3(16, 16), dim3(256), 0, stream>>>(P0, Bs0, P1, 762, 1016);
  comp_kernel<<<dim3(16, 16), dim3(256), 0, stream>>>(P1, Bs1, P0, 1016, 1270);
  comp_kernel<<<dim3(16, 16), dim3(256), 0, stream>>>(P0, Bs2, P1, 1270, 1524);

  zero_kernel<<<dim3(4096), dim3(256), 0, stream>>>((uint4*)(ws + 33587200), 25165824 / 16);
  // chunks 6,7 + 8
  leaf_kernel<254><<<dim3(512), dim3(256), 0, stream>>>(cs, Bs0, Bs1, Bs1, 6, 0);
  leaf_kernel<15><<<dim3(256), dim3(256), 0, stream>>>(cs, Bs2, Bs2, Bs2, 8, 0);
  comp_kernel<<<dim3(16, 16), dim3(256), 0, stream>>>(P1, Bs0, P0, 1524, 1778);
  comp_kernel<<<dim3(16, 16), dim3(256), 0, stream>>>(P0, Bs1, P1, 1778, 2032);
  comp_kernel<<<dim3(16, 16), dim3(256), 0, stream>>>(P1, Bs2, P0, 2032, 2047);

  // x -> bf16 into overlay (cs/B regions dead now), then final GEMM
  cvt_kernel<<<dim3(16384), dim3(256), 0, stream>>>((const float4*)x, (ushort4*)xb,
                                                    MROWS * NN / 4);
  gemm_kernel<<<dim3(MROWS / BM, NN / BN), dim3(256), 0, stream>>>(xb, P0, bias, out);
}

// Round 13
// 963.459 us; speedup vs baseline: 1.0199x; 1.0199x over previous
//
#include <hip/hip_runtime.h>
#include <hip/hip_bf16.h>

#define NN      2048
#define NSTEPS  2047
#define MROWS   8192
#define PADK    8

typedef __attribute__((ext_vector_type(8))) __bf16 bf16x8;
typedef __attribute__((ext_vector_type(4))) float  f32x4;
typedef __attribute__((ext_vector_type(2))) float  f32x2;

struct LeafOuts { unsigned short* p[8]; };

__device__ __forceinline__ unsigned short f2bf(float f) {
  unsigned int u = __float_as_uint(f);
  u += 0x7fffu + ((u >> 16) & 1u);   // RNE
  return (unsigned short)(u >> 16);
}

__device__ __forceinline__ void gload_lds16(const void* g, void* l) {
  __builtin_amdgcn_global_load_lds((const __attribute__((address_space(1))) void*)g,
                                   (__attribute__((address_space(3))) void*)l, 16, 0, 0);
}

// DPP wave-wide lane shifts (VALU pipe). Verified rounds 6-12.
template<int CTRL>
__device__ __forceinline__ float dppf(float v) {
  return __int_as_float(__builtin_amdgcn_update_dpp(
      __float_as_int(v), __float_as_int(v), CTRL, 0xf, 0xf, false));
}
#define DPP_UP 0x138
#define DPP_DN 0x130

// Packed fp32 rotation math. Verified rounds 7-12.
__device__ __forceinline__ f32x2 pk_smul(f32x2 cs, f32x2 v) {
  f32x2 d;
  asm("v_pk_mul_f32 %0, %1, %2 op_sel:[1,0] op_sel_hi:[1,1]"
      : "=v"(d) : "v"(cs), "v"(v));
  return d;
}
__device__ __forceinline__ f32x2 pk_cfma(f32x2 cs, f32x2 v, f32x2 a) {
  f32x2 d;
  asm("v_pk_fma_f32 %0, %1, %2, %3 op_sel:[0,0,0] op_sel_hi:[0,1,1]"
      : "=v"(d) : "v"(cs), "v"(v), "v"(a));
  return d;
}
__device__ __forceinline__ f32x2 pk_cfma_neg(f32x2 cs, f32x2 v, f32x2 a) {
  f32x2 d;
  asm("v_pk_fma_f32 %0, %1, %2, %3 op_sel:[0,0,0] op_sel_hi:[0,1,1] neg_lo:[0,0,1] neg_hi:[0,0,1]"
      : "=v"(d) : "v"(cs), "v"(v), "v"(a));
  return d;
}

// ---- angles -> (cos,sin), layout cs[step][pair] (8 KB/slice)
__global__ __launch_bounds__(256) void prep_kernel(
    const float* __restrict__ angles, float2* __restrict__ cs) {
  int idx = blockIdx.x * 256 + threadIdx.x;
  if (idx >= NSTEPS * 1024) return;
  float s, c;
  sincosf(angles[idx], &s, &c);
  cs[idx] = make_float2(c, s);
}

// ---- x fp32 -> bf16
__global__ __launch_bounds__(256) void cvt_kernel(
    const float4* __restrict__ x, ushort4* __restrict__ xb, int n4) {
  int idx = blockIdx.x * 256 + threadIdx.x;
  if (idx >= n4) return;
  float4 v = x[idx];
  ushort4 o;
  o.x = f2bf(v.x); o.y = f2bf(v.y); o.z = f2bf(v.z); o.w = f2bf(v.w);
  xb[idx] = o;
}

// ---- zero scratch region (grid-stride)
__global__ __launch_bounds__(256) void zero_kernel(uint4* __restrict__ p, int n) {
  int idx = blockIdx.x * 256 + threadIdx.x;
  const int stride = gridDim.x * 256;
  const uint4 z = make_uint4(0, 0, 0, 0);
  for (; idx < n; idx += stride) p[idx] = z;
}

// ---- leaf: build chunk matrix B_c rows by windowed wave-autonomous conveyor.
// Body byte-identical to round-12-verified kernel; only output selection changed
// (8-chunk merged dispatch, block-uniform pointer pick from struct arg).
template<int LC>
__global__ __launch_bounds__(256) void leaf_kernel(
    const char* __restrict__ csb, LeafOuts outs, int c_base, int first_rm) {
  const int tid  = threadIdx.x;
  const int lane = tid & 63;
  const int cl   = blockIdx.x >> 8;                      // chunk-local 0..7
  const int v    = ((blockIdx.x & 255) << 2) + (tid >> 6);
  const int c    = c_base + cl;
  const int t0   = 254 * c;
  unsigned short* out = outs.p[cl];
  const bool rm = (first_rm != 0) && (cl == 0);

  const int pA = 2 * v, pB = 2 * v + 1;
  const int kA = (pA <= 1023) ? pA : 2047 - pA;
  const int kBp = (pB <= 1023) ? pB : 2047 - pB;
  const int kmin = min(kA, kBp);
  int kb = (kmin - 254) & ~1;
  kb = min(max(kb, 0), 512);
  const bool l0 = (lane == 0), l63 = (lane == 63);
  const bool c0l0  = (kb == 0)   && l0;
  const bool cTl63 = (kb == 512) && l63;

  // state: elem e <-> pair k = kb + 8*lane + e; F slot = pos k, S slot = pos 2047-k
  f32x2 FF[8], SS[8];
#pragma unroll
  for (int e = 0; e < 8; ++e) {
    const int k = kb + 8 * lane + e, m = 2047 - k;
    FF[e] = (f32x2){(k == pA) ? 1.f : 0.f, (k == pB) ? 1.f : 0.f};
    SS[e] = (f32x2){(m == pA) ? 1.f : 0.f, (m == pB) ? 1.f : 0.f};
  }

  // cs: lane's 8 pairs = 64B at slice + kb*8 + 64*lane (kb even -> 16B aligned)
  const char* gpE = csb + (size_t)t0 * 8192 + kb * 8 + 64 * lane;
  const char* gpO = gpE + 8192;
  float4 cE0 = ((const float4*)gpE)[0], cE1 = ((const float4*)gpE)[1];
  float4 cE2 = ((const float4*)gpE)[2], cE3 = ((const float4*)gpE)[3];
  float4 cO0 = ((const float4*)gpO)[0], cO1 = ((const float4*)gpO)[1];
  float4 cO2 = ((const float4*)gpO)[2], cO3 = ((const float4*)gpO)[3];
  gpE += 16384; gpO += 16384;

#define CP(CV, K) (((const f32x2*)&(CV))[(K)])

#define ROTE(E, CPp) { \
    const int rF = ((E) - PHI) & 7, rS = ((E) + PHI) & 7; \
    const f32x2 cp_ = (CPp); \
    const f32x2 t_ = pk_smul(cp_, SS[rS]); \
    const f32x2 u_ = pk_smul(cp_, FF[rF]); \
    FF[rF] = pk_cfma(cp_, FF[rF], t_); \
    SS[rS] = pk_cfma_neg(cp_, SS[rS], u_); }

#define LSTEP(PHI_, C0, C1, C2, C3, GP) { \
    const int PHI = (PHI_); \
    const int pF = (7 - PHI) & 7, pT = (8 - PHI) & 7; \
    ROTE(0, CP(C0, 0)) ROTE(1, CP(C0, 1)) \
    ROTE(2, CP(C1, 0)) ROTE(3, CP(C1, 1)) \
    ROTE(4, CP(C2, 0)) ROTE(5, CP(C2, 1)) \
    ROTE(6, CP(C3, 0)) ROTE(7, CP(C3, 1)) \
    const f32x2 Fo = FF[pF], So = SS[PHI], St = FF[pT]; \
    f32x2 fi, sd; \
    fi.x = dppf<DPP_UP>(Fo.x); fi.y = dppf<DPP_UP>(Fo.y); \
    sd.x = dppf<DPP_DN>(So.x); sd.y = dppf<DPP_DN>(So.y); \
    C0 = ((const float4*)GP)[0]; C1 = ((const float4*)GP)[1]; \
    C2 = ((const float4*)GP)[2]; C3 = ((const float4*)GP)[3]; \
    GP += 16384; \
    const f32x2 z2 = {0.f, 0.f}; \
    const f32x2 xF = c0l0 ? St : z2; \
    const f32x2 xS = cTl63 ? Fo : z2; \
    FF[pF]  = l0  ? xF : fi; \
    SS[PHI] = l63 ? xS : sd; \
    FF[pT]  = c0l0 ? So : FF[pT]; \
  }

  constexpr int ITERS = LC / 8;
  constexpr int TAIL  = LC & 7;
#pragma unroll 1
  for (int it = 0; it < ITERS; ++it) {
    LSTEP(0, cE0, cE1, cE2, cE3, gpE)
    LSTEP(1, cO0, cO1, cO2, cO3, gpO)
    LSTEP(2, cE0, cE1, cE2, cE3, gpE)
    LSTEP(3, cO0, cO1, cO2, cO3, gpO)
    LSTEP(4, cE0, cE1, cE2, cE3, gpE)
    LSTEP(5, cO0, cO1, cO2, cO3, gpO)
    LSTEP(6, cE0, cE1, cE2, cE3, gpE)
    LSTEP(7, cO0, cO1, cO2, cO3, gpO)
  }
  if constexpr (TAIL >= 1) LSTEP(0, cE0, cE1, cE2, cE3, gpE)
  if constexpr (TAIL >= 2) LSTEP(1, cO0, cO1, cO2, cO3, gpO)
  if constexpr (TAIL >= 3) LSTEP(2, cE0, cE1, cE2, cE3, gpE)
  if constexpr (TAIL >= 4) LSTEP(3, cO0, cO1, cO2, cO3, gpO)
  if constexpr (TAIL >= 5) LSTEP(4, cE0, cE1, cE2, cE3, gpE)
  if constexpr (TAIL >= 6) LSTEP(5, cO0, cO1, cO2, cO3, gpO)
  if constexpr (TAIL >= 7) LSTEP(6, cE0, cE1, cE2, cE3, gpE)

  // readout at T=LC: F elem e in FF[(e-LC)&7]; S elem e in SS[(e+LC)&7].
  constexpr int RPH = LC & 7;
  const int tend = t0 + LC;
  const int rA = (pA == 0) ? 0 : ((pA - 1 - t0 + 4094) % 2047) + 1;
  const int rB = ((pB - 1 - t0 + 4094) % 2047) + 1;
#pragma unroll
  for (int e = 0; e < 8; ++e) {
    const int k = kb + 8 * lane + e;
    const int lF = (k == 0) ? 0 : ((k - 1 - tend + 4094) % 2047) + 1;
    const int lS = ((2046 - k - tend + 4094) % 2047) + 1;
    const f32x2 fv = FF[(e - RPH) & 7];
    const f32x2 sv = SS[(e + RPH) & 7];
    if (rm) {
      out[(size_t)rA * NN + lF] = f2bf(fv.x);
      out[(size_t)rB * NN + lF] = f2bf(fv.y);
      out[(size_t)rA * NN + lS] = f2bf(sv.x);
      out[(size_t)rB * NN + lS] = f2bf(sv.y);
    } else {
      out[(size_t)lF * NN + rA] = f2bf(fv.x);
      out[(size_t)lF * NN + rB] = f2bf(fv.y);
      out[(size_t)lS * NN + rA] = f2bf(sv.x);
      out[(size_t)lS * NN + rB] = f2bf(sv.y);
    }
  }
}

// κ-range of a cyclic position arc [a, a+len-1] in [1..2047], κ(p)=min(p,2047-p)
__device__ __forceinline__ void arc_kr(int a, int len, int& lo, int& hi) {
  int last = a + len - 1; if (last > 2047) last -= 2047;
  const int k1 = min(a, 2047 - a), k2 = min(last, 2047 - last);
  lo = min(k1, k2); hi = max(k1, k2);
  int d;
  d = 1023 - a; if (d < 0) d += 2047; if (d < len) hi = 1023;
  d = 1024 - a; if (d < 0) d += 2047; if (d < len) hi = 1023;
  d = 2047 - a; if (d < 0) d += 2047; if (d < len) lo = 0;
  d = 1    - a; if (d < 0) d += 2047; if (d < len) lo = min(lo, 1);
}

#define BM 128
#define BN 128
#define BK 32

// ---- comp: C = A * Bt^T (2048^3), bf16 out, K-tiles band-skipped by cone test.
__global__ __launch_bounds__(256) void comp_kernel(
    const unsigned short* __restrict__ A, const unsigned short* __restrict__ B,
    unsigned short* __restrict__ C, int ta, int tb) {
  __shared__ unsigned short As[BM * BK];
  __shared__ unsigned short Bs[BN * BK];
  const int tid  = threadIdx.x;
  const int lane = tid & 63;
  const int wave = tid >> 6;
  const int bm = blockIdx.x, bn = blockIdx.y;
  const int wm = wave & 1, wn = wave >> 1;

  const int n0 = bn * BN;
  int qlo, qhi;
  {
    const int nfirst = (n0 == 0) ? 1 : n0;
    const int a = ((nfirst - 1 + tb) % 2047) + 1;
    const int len = (n0 == 0) ? (BN - 1) : BN;
    arc_kr(a, len, qlo, qhi);
    if (n0 == 0) qlo = 0;
  }
  const int L = tb - ta;
  const int KAc = max(qlo - L - PADK, 0);
  const int KBc = min(qhi + L + PADK, 1023);

  const int srow = wave * 16 + (lane >> 2);
  const int scol = (lane & 3) * 8;
  const unsigned short* Ag = A + (size_t)(bm * BM + srow) * NN + scol;
  const unsigned short* Bg = B + (size_t)(bn * BN + srow) * NN + scol;

  const int fm = lane & 15;
  const int kbr = lane >> 4;

  f32x4 acc[4][4];
#pragma unroll
  for (int a_ = 0; a_ < 4; ++a_)
#pragma unroll
    for (int b_ = 0; b_ < 4; ++b_) acc[a_][b_] = (f32x4){0.f, 0.f, 0.f, 0.f};

  for (int kt = 0; kt < NN / BK; ++kt) {
    const int k0 = kt * BK;
    {
      const int kfirst = (k0 == 0) ? 1 : k0;
      const int a2 = ((kfirst - 1 + ta) % 2047) + 1;
      const int len2 = (k0 == 0) ? (BK - 1) : BK;
      int tlo, thi; arc_kr(a2, len2, tlo, thi);
      if (k0 == 0) tlo = 0;
      if (thi < KAc || tlo > KBc) continue;
    }
#pragma unroll
    for (int it = 0; it < 2; ++it) {
      gload_lds16(Ag + (size_t)(it * 64) * NN + k0, &As[wave * 512 + it * 2048]);
      gload_lds16(Bg + (size_t)(it * 64) * NN + k0, &Bs[wave * 512 + it * 2048]);
    }
    __syncthreads();

    bf16x8 af[4], bfr[4];
#pragma unroll
    for (int a_ = 0; a_ < 4; ++a_)
      af[a_] = *(const bf16x8*)&As[(wm * 64 + a_ * 16 + fm) * BK + kbr * 8];
#pragma unroll
    for (int b_ = 0; b_ < 4; ++b_)
      bfr[b_] = *(const bf16x8*)&Bs[(wn * 64 + b_ * 16 + fm) * BK + kbr * 8];
#pragma unroll
    for (int a_ = 0; a_ < 4; ++a_)
#pragma unroll
      for (int b_ = 0; b_ < 4; ++b_)
        acc[a_][b_] = __builtin_amdgcn_mfma_f32_16x16x32_bf16(af[a_], bfr[b_], acc[a_][b_], 0, 0, 0);
    __syncthreads();
  }

  const int row_in = (lane >> 4) * 4;
#pragma unroll
  for (int a_ = 0; a_ < 4; ++a_) {
#pragma unroll
    for (int b_ = 0; b_ < 4; ++b_) {
      const int gn = bn * BN + wn * 64 + b_ * 16 + fm;
#pragma unroll
      for (int v = 0; v < 4; ++v) {
        const int gm = bm * BM + wm * 64 + a_ * 16 + row_in + v;
        C[(size_t)gm * NN + gn] = f2bf(acc[a_][b_][v]);
      }
    }
  }
}

// ---- final: out = x_bf16 * U^T + bias (fp32 out). Verified rounds 1-12.
__global__ __launch_bounds__(256) void gemm_kernel(
    const unsigned short* __restrict__ A, const unsigned short* __restrict__ B,
    const float* __restrict__ bias, float* __restrict__ C) {
  __shared__ unsigned short As[BM * BK];
  __shared__ unsigned short Bs[BN * BK];
  const int tid  = threadIdx.x;
  const int lane = tid & 63;
  const int wave = tid >> 6;
  const int bm = blockIdx.x, bn = blockIdx.y;
  const int wm = wave & 1, wn = wave >> 1;

  const int srow = wave * 16 + (lane >> 2);
  const int scol = (lane & 3) * 8;
  const unsigned short* Ag = A + (size_t)(bm * BM + srow) * NN + scol;
  const unsigned short* Bg = B + (size_t)(bn * BN + srow) * NN + scol;

  const int fm = lane & 15;
  const int kbr = lane >> 4;

  f32x4 acc[4][4];
#pragma unroll
  for (int a_ = 0; a_ < 4; ++a_)
#pragma unroll
    for (int b_ = 0; b_ < 4; ++b_) acc[a_][b_] = (f32x4){0.f, 0.f, 0.f, 0.f};

  for (int kt = 0; kt < NN / BK; ++kt) {
    const int k0 = kt * BK;
#pragma unroll
    for (int it = 0; it < 2; ++it) {
      gload_lds16(Ag + (size_t)(it * 64) * NN + k0, &As[wave * 512 + it * 2048]);
      gload_lds16(Bg + (size_t)(it * 64) * NN + k0, &Bs[wave * 512 + it * 2048]);
    }
    __syncthreads();

    bf16x8 af[4], bfr[4];
#pragma unroll
    for (int a_ = 0; a_ < 4; ++a_)
      af[a_] = *(const bf16x8*)&As[(wm * 64 + a_ * 16 + fm) * BK + kbr * 8];
#pragma unroll
    for (int b_ = 0; b_ < 4; ++b_)
      bfr[b_] = *(const bf16x8*)&Bs[(wn * 64 + b_ * 16 + fm) * BK + kbr * 8];
#pragma unroll
    for (int a_ = 0; a_ < 4; ++a_)
#pragma unroll
      for (int b_ = 0; b_ < 4; ++b_)
        acc[a_][b_] = __builtin_amdgcn_mfma_f32_16x16x32_bf16(af[a_], bfr[b_], acc[a_][b_], 0, 0, 0);
    __syncthreads();
  }

  const int row_in = (lane >> 4) * 4;
#pragma unroll
  for (int a_ = 0; a_ < 4; ++a_) {
#pragma unroll
    for (int b_ = 0; b_ < 4; ++b_) {
      const int gn = bn * BN + wn * 64 + b_ * 16 + fm;
      const float bv = bias[gn];
#pragma unroll
      for (int v = 0; v < 4; ++v) {
        const int gm = bm * BM + wm * 64 + a_ * 16 + row_in + v;
        C[(size_t)gm * NN + gn] = acc[a_][b_][v] + bv;
      }
    }
  }
}

extern "C" void kernel_launch(void* const* d_in, const int* in_sizes, int n_in,
                              void* d_out, int out_size, void* d_ws, size_t ws_size,
                              hipStream_t stream) {
  const float* x      = (const float*)d_in[0];
  const float* angles = (const float*)d_in[1];
  const float* bias   = (const float*)d_in[2];
  float* out = (float*)d_out;

  char* ws = (char*)d_ws;
  unsigned short* P0  = (unsigned short*)(ws + 0);         //  8,388,608
  unsigned short* P1  = (unsigned short*)(ws + 8388608);   //  8,388,608
  char*           cs  = ws + 16777216;                     // 16,809,984 (2052 slices)
  unsigned short* B7  = (unsigned short*)(ws + 33587200);  //  8,388,608
  unsigned short* B8  = (unsigned short*)(ws + 41975808);  //  8,388,608 -> end 50,364,416
  unsigned short* xb  = (unsigned short*)(ws + 16777216);  // overlay (after comps)

  // B1..B6 live in d_out (67.1 MB; final gemm overwrites all of d_out at the end)
  char* ob = (char*)d_out;
  unsigned short* B1 = (unsigned short*)(ob + 0);
  unsigned short* B2 = (unsigned short*)(ob + 8388608);
  unsigned short* B3 = (unsigned short*)(ob + 16777216);
  unsigned short* B4 = (unsigned short*)(ob + 25165824);
  unsigned short* B5 = (unsigned short*)(ob + 33554432);
  unsigned short* B6 = (unsigned short*)(ob + 41943040);   // end 50,331,648 <= 67,108,864

  prep_kernel<<<dim3(8188), dim3(256), 0, stream>>>(angles, (float2*)cs);
  zero_kernel<<<dim3(2048), dim3(256), 0, stream>>>((uint4*)ob, 50331648 / 16);
  zero_kernel<<<dim3(1024), dim3(256), 0, stream>>>((uint4*)P0, 8388608 / 16);
  zero_kernel<<<dim3(1024), dim3(256), 0, stream>>>((uint4*)(ws + 33587200), 16777216 / 16);

  // single merged leaf dispatch: chunks 0..7 (chunk 0 -> P0 row-major)
  LeafOuts lo_main;
  lo_main.p[0] = P0; lo_main.p[1] = B1; lo_main.p[2] = B2; lo_main.p[3] = B3;
  lo_main.p[4] = B4; lo_main.p[5] = B5; lo_main.p[6] = B6; lo_main.p[7] = B7;
  leaf_kernel<254><<<dim3(2048), dim3(256), 0, stream>>>(cs, lo_main, 0, 1);
  // chunk 8 (15 steps)
  LeafOuts lo_tail;
  for (int i = 0; i < 8; ++i) lo_tail.p[i] = B8;
  leaf_kernel<15><<<dim3(256), dim3(256), 0, stream>>>(cs, lo_tail, 8, 0);

  // composition chain: P = B0 * B1 * ... * B8
  comp_kernel<<<dim3(16, 16), dim3(256), 0, stream>>>(P0, B1, P1,  254,  508);
  comp_kernel<<<dim3(16, 16), dim3(256), 0, stream>>>(P1, B2, P0,  508,  762);
  comp_kernel<<<dim3(16, 16), dim3(256), 0, stream>>>(P0, B3, P1,  762, 1016);
  comp_kernel<<<dim3(16, 16), dim3(256), 0, stream>>>(P1, B4, P0, 1016, 1270);
  comp_kernel<<<dim3(16, 16), dim3(256), 0, stream>>>(P0, B5, P1, 1270, 1524);
  comp_kernel<<<dim3(16, 16), dim3(256), 0, stream>>>(P1, B6, P0, 1524, 1778);
  comp_kernel<<<dim3(16, 16), dim3(256), 0, stream>>>(P0, B7, P1, 1778, 2032);
  comp_kernel<<<dim3(16, 16), dim3(256), 0, stream>>>(P1, B8, P0, 2032, 2047);

  // x -> bf16 into overlay (cs/B7/B8 dead now), then final GEMM overwrites d_out
  cvt_kernel<<<dim3(16384), dim3(256), 0, stream>>>((const float4*)x, (ushort4*)xb,
                                                    MROWS * NN / 4);
  gemm_kernel<<<dim3(MROWS / BM, NN / BN), dim3(256), 0, stream>>>(xb, P0, bias, out);
}